// Round 8
// baseline (116.330 us; speedup 1.0000x reference)
//
#include <hip/hip_runtime.h>

// Problem constants (from reference setup_inputs): B=2, H=W=128.
#define B_ITEMS 2
#define W_IMG   128
#define N_PTS   16384          // H*W
#define CH_GRID 2048           // >= max Utot = 4*ceil(16384/32)

// ---------------------------------------------------------------------------
// Kernel 1: compaction (unchanged from R7 — correct & fast). 256 blocks x 256
// thr; target s = blockIdx.x>>6 (0:P0 1:P1 2:G0 3:G1). Block-local ballot
// scan -> ONE global atomicAdd per block (cnt zeroed by 16-B memset node).
// Writes per valid point:
//   raw[pos] = (x, y, z, |q|^2)        row side
//   tf [pos] = (-2x, -2y, -2z, |q|^2)  col side: d = |p|^2 + fma3(p, tf)
// Block 0/tid 0 zeroes out[0] (stream order precedes chamfer's atomicAdds).
// ---------------------------------------------------------------------------
__global__ __launch_bounds__(256) void prep_kernel(
        const float* __restrict__ pred,
        const float* __restrict__ gt,
        const int*   __restrict__ mask,
        const float* fxp, const float* fyp,
        const float* cxp, const float* cyp,
        int*    __restrict__ cnt,       // [0]=np0 [1]=np1 [2]=ng0 [3]=ng1
        float4* __restrict__ pR, float4* __restrict__ gR,   // raw   [B][N]
        float4* __restrict__ pT, float4* __restrict__ gT,   // transf[B][N]
        float*  __restrict__ out) {
    int s    = blockIdx.x >> 6;         // 0:P0 1:P1 2:G0 3:G1
    int b    = s & 1;
    int isG  = s >> 1;
    int tid  = threadIdx.x;
    int idx  = (blockIdx.x & 63) * 256 + tid;
    int lane = tid & 63, w = tid >> 6;

    if (blockIdx.x == 0 && tid == 0) out[0] = 0.0f;

    float x, y, z;
    if (!isG) {
        float fx = *fxp, fy = *fyp, cx = *cxp, cy = *cyp;
        float u = (float)(idx & (W_IMG - 1));
        float v = (float)(idx >> 7);
        z = pred[b * N_PTS + idx];
        x = (u - cx) / fx * z;
        y = (v - cy) / fy * z;
    } else {
        x = gt[(b * 3 + 0) * N_PTS + idx];
        y = gt[(b * 3 + 1) * N_PTS + idx];
        z = gt[(b * 3 + 2) * N_PTS + idx];
    }
    int  mv = mask[b * N_PTS + idx];
    bool ok = (mv > 0) && (((x + y) + z) != 0.0f);

    unsigned long long bal = __ballot(ok);
    int nw  = __popcll(bal);
    int pre = __popcll(bal & ((1ull << lane) - 1ull));

    __shared__ int wbase[4];
    __shared__ int blockbase;
    if (lane == 0) wbase[w] = nw;
    __syncthreads();
    if (tid == 0) {
        int s0 = 0;
#pragma unroll
        for (int i = 0; i < 4; ++i) { int t = wbase[i]; wbase[i] = s0; s0 += t; }
        blockbase = s0 ? atomicAdd(&cnt[s], s0) : 0;
    }
    __syncthreads();

    if (ok) {
        int pos = blockbase + wbase[w] + pre;
        float ps = fmaf(z, z, fmaf(y, y, x * x));
        float4* __restrict__ raw = (isG ? gR : pR) + b * N_PTS;
        float4* __restrict__ tf  = (isG ? gT : pT) + b * N_PTS;
        raw[pos] = make_float4(x, y, z, ps);
        tf[pos]  = make_float4(-2.0f * x, -2.0f * y, -2.0f * z, ps);
    }
}

// ---------------------------------------------------------------------------
// Kernel 2: unfused direct-sum chamfer, 4 VALU ops/pair, ALL-SCALAR hot loop
// (R7 post-mortem: lambda+array ping-pong was demoted to scratch -> 5.6 MB
// of spill writes; no arrays can exist here). Unit = 32 A-rows x all B-cols;
// contiguous unit ids -> uniform CU fill. Block 256 = (tc = tid&31 lanes ->
// coalesced 512B loads; tr = tid>>5). Thread: 4 rows x 4 cols per 128-col
// tile; 2 tiles/iteration with all 8 loads issued before compute (ILP).
// Row-min finishes in-register; fold over tc (5 shfl_xor), LDS fold over
// waves, gate row<na, add |p|^2, clamp, one atomicAdd per unit.
// ---------------------------------------------------------------------------
#define COMP4(c)                                                              \
    do {                                                                      \
        rm0 = fminf(rm0, fmaf(px0, (c).x, fmaf(py0, (c).y, fmaf(pz0, (c).z, (c).w)))); \
        rm1 = fminf(rm1, fmaf(px1, (c).x, fmaf(py1, (c).y, fmaf(pz1, (c).z, (c).w)))); \
        rm2 = fminf(rm2, fmaf(px2, (c).x, fmaf(py2, (c).y, fmaf(pz2, (c).z, (c).w)))); \
        rm3 = fminf(rm3, fmaf(px3, (c).x, fmaf(py3, (c).y, fmaf(pz3, (c).z, (c).w)))); \
    } while (0)

__global__ __launch_bounds__(256, 6) void chamfer_kernel(
        const int*    __restrict__ cnt,
        const float4* __restrict__ pR, const float4* __restrict__ gR,
        const float4* __restrict__ pT, const float4* __restrict__ gT,
        float* __restrict__ out) {
    int np0 = cnt[0], np1 = cnt[1], ng0 = cnt[2], ng1 = cnt[3];
    int naArr[4] = {np0, ng0, np1, ng1};
    int nbArr[4] = {ng0, np0, ng1, np1};
    const float4* Arow[4] = {pR, gR, pR + N_PTS, gR + N_PTS};
    const float4* Bcol[4] = {gT, pT, gT + N_PTS, pT + N_PTS};

    int units[4];
    int Utot = 0;
#pragma unroll
    for (int i = 0; i < 4; ++i) {
        units[i] = (naArr[i] > 0 && nbArr[i] > 0) ? ((naArr[i] + 31) >> 5) : 0;
        Utot += units[i];
    }
    int u = blockIdx.x;
    if (u >= Utot) return;
    int s = 0;
    while (u >= units[s]) { u -= units[s]; ++s; }
    int na = naArr[s], nb = nbArr[s];
    const float4* __restrict__ A  = Arow[s];
    const float4* __restrict__ Bp = Bcol[s];
    int rowbase = u * 32;

    int tid = threadIdx.x;
    int tc = tid & 31, tr = tid >> 5;

    // 4 rows/thread: row = rowbase + a*8 + tr  (junk rows >= na gated at end;
    // ws poison 0xAA reads as ~-3e-13, finite -> no NaN/Inf hazard)
    float4 r0 = A[rowbase +  0 + tr];
    float4 r1 = A[rowbase +  8 + tr];
    float4 r2 = A[rowbase + 16 + tr];
    float4 r3 = A[rowbase + 24 + tr];
    float px0 = r0.x, py0 = r0.y, pz0 = r0.z;
    float px1 = r1.x, py1 = r1.y, pz1 = r1.z;
    float px2 = r2.x, py2 = r2.y, pz2 = r2.z;
    float px3 = r3.x, py3 = r3.y, pz3 = r3.z;
    float rm0 = 3.4e38f, rm1 = 3.4e38f, rm2 = 3.4e38f, rm3 = 3.4e38f;

    int full = nb >> 7;                          // full 128-col tiles
    int t = 0;
    for (; t + 2 <= full; t += 2) {
        const float4* __restrict__ bp = Bp + t * 128 + tc;
        float4 u0 = bp[0],   u1 = bp[32],  u2 = bp[64],  u3 = bp[96];
        float4 v0 = bp[128], v1 = bp[160], v2 = bp[192], v3 = bp[224];
        COMP4(u0); COMP4(u1); COMP4(u2); COMP4(u3);
        COMP4(v0); COMP4(v1); COMP4(v2); COMP4(v3);
    }
    if (t < full) {
        const float4* __restrict__ bp = Bp + t * 128 + tc;
        float4 u0 = bp[0], u1 = bp[32], u2 = bp[64], u3 = bp[96];
        COMP4(u0); COMP4(u1); COMP4(u2); COMP4(u3);
    }
    if (nb & 127) {                              // masked tail tile
        int jb = full * 128 + tc;
#pragma unroll
        for (int q = 0; q < 4; ++q) {
            int j = jb + q * 32;                 // <= 16383 always
            float4 v = Bp[j];
            float4 c;
            bool okc = j < nb;
            c.x = okc ? v.x : 0.0f;
            c.y = okc ? v.y : 0.0f;
            c.z = okc ? v.z : 0.0f;
            c.w = okc ? v.w : 3.4e38f;           // masked col never wins min
            COMP4(c);
        }
    }

    // fold over tc (lane bits 0..4)
#pragma unroll
    for (int off = 1; off <= 16; off <<= 1) {
        rm0 = fminf(rm0, __shfl_xor(rm0, off, 64));
        rm1 = fminf(rm1, __shfl_xor(rm1, off, 64));
        rm2 = fminf(rm2, __shfl_xor(rm2, off, 64));
        rm3 = fminf(rm3, __shfl_xor(rm3, off, 64));
    }
    __shared__ float smin[32];
    if (tc == 0) {                               // lanes 0 & 32 of each wave
        smin[ 0 + tr] = rm0;
        smin[ 8 + tr] = rm1;
        smin[16 + tr] = rm2;
        smin[24 + tr] = rm3;
    }
    __syncthreads();
    if (tid < 32) {
        int row = rowbase + tid;
        float v  = smin[tid];
        float ps = A[row].w;                     // |p|^2 (L1-hot reload)
        float contrib = (row < na) ? fmaxf(v + ps, 0.0f) : 0.0f;
#pragma unroll
        for (int off = 16; off > 0; off >>= 1)
            contrib += __shfl_down(contrib, off, 32);   // width 32: stays in group
        if (tid == 0) atomicAdd(out, contrib * (1.0f / B_ITEMS));
    }
}

extern "C" void kernel_launch(void* const* d_in, const int* in_sizes, int n_in,
                              void* d_out, int out_size, void* d_ws, size_t ws_size,
                              hipStream_t stream) {
    const float* pred = (const float*)d_in[0];
    const float* gt   = (const float*)d_in[1];
    const int*   mask = (const int*)  d_in[2];
    const float* fx   = (const float*)d_in[3];
    const float* fy   = (const float*)d_in[4];
    const float* cx   = (const float*)d_in[5];
    const float* cy   = (const float*)d_in[6];
    float* out = (float*)d_out;

    // ws: [0,256) cnt | pR 512K | gR 512K | pT 512K | gT 512K  (~2.1 MB)
    char* ws = (char*)d_ws;
    size_t SEG = (size_t)B_ITEMS * N_PTS * 16;
    int*    cnt = (int*)ws;
    float4* pR  = (float4*)(ws + 256);
    float4* gR  = (float4*)(ws + 256 + SEG);
    float4* pT  = (float4*)(ws + 256 + 2 * SEG);
    float4* gT  = (float4*)(ws + 256 + 3 * SEG);

    hipMemsetAsync(cnt, 0, 16, stream);

    prep_kernel<<<dim3(256), 256, 0, stream>>>(
        pred, gt, mask, fx, fy, cx, cy, cnt, pR, gR, pT, gT, out);

    chamfer_kernel<<<dim3(CH_GRID), 256, 0, stream>>>(
        cnt, pR, gR, pT, gT, out);
}

// Round 9
// 104.197 us; speedup vs baseline: 1.1164x; 1.1164x over previous
//
#include <hip/hip_runtime.h>

// Problem constants (from reference setup_inputs): B=2, H=W=128.
#define B_ITEMS 2
#define W_IMG   128
#define N_PTS   16384          // H*W
#define CH_GRID 1024           // >= max Utot = 4*ceil(16384/64)

// ---------------------------------------------------------------------------
// Kernel 1: compaction (unchanged since R7 — proven correct & fast). 256
// blocks x 256 thr; target s = blockIdx.x>>6 (0:P0 1:P1 2:G0 3:G1).
// Block-local ballot scan -> ONE global atomicAdd per block.
//   raw[pos] = (x, y, z, |q|^2)        row side
//   tf [pos] = (-2x, -2y, -2z, |q|^2)  col side: d = |p|^2 + fma3(p, tf)
// Block 0/tid 0 zeroes out[0] (stream order precedes chamfer's atomicAdds).
// ---------------------------------------------------------------------------
__global__ __launch_bounds__(256) void prep_kernel(
        const float* __restrict__ pred,
        const float* __restrict__ gt,
        const int*   __restrict__ mask,
        const float* fxp, const float* fyp,
        const float* cxp, const float* cyp,
        int*    __restrict__ cnt,       // [0]=np0 [1]=np1 [2]=ng0 [3]=ng1
        float4* __restrict__ pR, float4* __restrict__ gR,   // raw   [B][N]
        float4* __restrict__ pT, float4* __restrict__ gT,   // transf[B][N]
        float*  __restrict__ out) {
    int s    = blockIdx.x >> 6;
    int b    = s & 1;
    int isG  = s >> 1;
    int tid  = threadIdx.x;
    int idx  = (blockIdx.x & 63) * 256 + tid;
    int lane = tid & 63, w = tid >> 6;

    if (blockIdx.x == 0 && tid == 0) out[0] = 0.0f;

    float x, y, z;
    if (!isG) {
        float fx = *fxp, fy = *fyp, cx = *cxp, cy = *cyp;
        float u = (float)(idx & (W_IMG - 1));
        float v = (float)(idx >> 7);
        z = pred[b * N_PTS + idx];
        x = (u - cx) / fx * z;
        y = (v - cy) / fy * z;
    } else {
        x = gt[(b * 3 + 0) * N_PTS + idx];
        y = gt[(b * 3 + 1) * N_PTS + idx];
        z = gt[(b * 3 + 2) * N_PTS + idx];
    }
    int  mv = mask[b * N_PTS + idx];
    bool ok = (mv > 0) && (((x + y) + z) != 0.0f);

    unsigned long long bal = __ballot(ok);
    int nw  = __popcll(bal);
    int pre = __popcll(bal & ((1ull << lane) - 1ull));

    __shared__ int wbase[4];
    __shared__ int blockbase;
    if (lane == 0) wbase[w] = nw;
    __syncthreads();
    if (tid == 0) {
        int s0 = 0;
#pragma unroll
        for (int i = 0; i < 4; ++i) { int t = wbase[i]; wbase[i] = s0; s0 += t; }
        blockbase = s0 ? atomicAdd(&cnt[s], s0) : 0;
    }
    __syncthreads();

    if (ok) {
        int pos = blockbase + wbase[w] + pre;
        float ps = fmaf(z, z, fmaf(y, y, x * x));
        float4* __restrict__ raw = (isG ? gR : pR) + b * N_PTS;
        float4* __restrict__ tf  = (isG ? gT : pT) + b * N_PTS;
        raw[pos] = make_float4(x, y, z, ps);
        tf[pos]  = make_float4(-2.0f * x, -2.0f * y, -2.0f * z, ps);
    }
}

// ---------------------------------------------------------------------------
// Kernel 2: unfused direct-sum chamfer, 4 VALU ops/pair, LDS double-buffered
// B staging (R8 post-mortem: register prefetch was collapsed by the
// compiler -> exposed L2 latency at 51% VALUBusy; LDS prefetch target
// cannot be collapsed). Unit = 64 A-rows x all B-cols, contiguous unit ids.
// Block 256 = (tc = tid&31, tr = tid>>5): thread owns 8 rows; per 256-col
// tile it global-loads ONE float4 (in flight under 256 VALU ops, ds_write
// at tile end), and ds_read_b128's 8 cols from LDS (latency ~120cyc, hidden;
// demand 64 B/cyc/CU < 85 B/cyc ceiling). Tail staged with sentinel w=+3e38
// -> uniform unmasked inner loop. One barrier/tile. Row-min in-register,
// fold over tc (5 shfl_xor), per-row |p|^2 + clamp, one atomicAdd per unit.
// ---------------------------------------------------------------------------
__global__ __launch_bounds__(256, 4) void chamfer_kernel(
        const int*    __restrict__ cnt,
        const float4* __restrict__ pR, const float4* __restrict__ gR,
        const float4* __restrict__ pT, const float4* __restrict__ gT,
        float* __restrict__ out) {
    int np0 = cnt[0], np1 = cnt[1], ng0 = cnt[2], ng1 = cnt[3];
    int naArr[4] = {np0, ng0, np1, ng1};
    int nbArr[4] = {ng0, np0, ng1, np1};
    const float4* Arow[4] = {pR, gR, pR + N_PTS, gR + N_PTS};
    const float4* Bcol[4] = {gT, pT, gT + N_PTS, pT + N_PTS};

    int units[4];
    int Utot = 0;
#pragma unroll
    for (int i = 0; i < 4; ++i) {
        units[i] = (naArr[i] > 0 && nbArr[i] > 0) ? ((naArr[i] + 63) >> 6) : 0;
        Utot += units[i];
    }
    int u = blockIdx.x;
    if (u >= Utot) return;
    int s = 0;
    while (u >= units[s]) { u -= units[s]; ++s; }
    int na = naArr[s], nb = nbArr[s];
    const float4* __restrict__ A  = Arow[s];
    const float4* __restrict__ Bp = Bcol[s];
    int rowbase = u * 64;

    int tid = threadIdx.x;
    int tc = tid & 31, tr = tid >> 5;

    // 8 rows/thread: row = rowbase + a*8 + tr (rows >= na gated at the end;
    // ws poison 0xAA reads as ~-3e-13, finite -> no NaN/Inf hazard).
    float px[8], py[8], pz[8], rm[8];
#pragma unroll
    for (int a = 0; a < 8; ++a) {
        float4 v = A[rowbase + a * 8 + tr];      // < N_PTS capacity always
        px[a] = v.x; py[a] = v.y; pz[a] = v.z;
        rm[a] = 3.4e38f;
    }

    __shared__ float4 sB[2][256];
    __shared__ float  smin[64];
    int ntiles = (nb + 255) >> 8;                // >= 1 (nb > 0 by gating)

    // stage tile 0 (branchless masked: clamp index, select sentinel)
    {
        int j = tid;
        float4 v = Bp[min(j, N_PTS - 1)];
        bool okc = j < nb;
        float4 r;
        r.x = okc ? v.x : 0.0f;
        r.y = okc ? v.y : 0.0f;
        r.z = okc ? v.z : 0.0f;
        r.w = okc ? v.w : 3.4e38f;               // sentinel col never wins min
        sB[0][tid] = r;
    }
    __syncthreads();

    for (int t = 0; t < ntiles; ++t) {
        float4 r;                                // prefetch tile t+1 (global)
        bool have = (t + 1 < ntiles);
        if (have) {
            int j = (t + 1) * 256 + tid;
            float4 v = Bp[min(j, N_PTS - 1)];
            bool okc = j < nb;
            r.x = okc ? v.x : 0.0f;
            r.y = okc ? v.y : 0.0f;
            r.z = okc ? v.z : 0.0f;
            r.w = okc ? v.w : 3.4e38f;
        }
        const float4* __restrict__ buf = sB[t & 1];
#pragma unroll
        for (int cb = 0; cb < 8; ++cb) {
            float4 c = buf[cb * 32 + tc];        // ds_read_b128, conflict-free
#pragma unroll
            for (int a = 0; a < 8; ++a)
                rm[a] = fminf(rm[a],
                    fmaf(px[a], c.x, fmaf(py[a], c.y, fmaf(pz[a], c.z, c.w))));
        }
        if (have) sB[(t + 1) & 1][tid] = r;      // write other buffer
        __syncthreads();                          // readers done + write visible
    }

    // fold over tc (lane bits 0..4)
#pragma unroll
    for (int a = 0; a < 8; ++a) {
        float v = rm[a];
        v = fminf(v, __shfl_xor(v, 1, 64));
        v = fminf(v, __shfl_xor(v, 2, 64));
        v = fminf(v, __shfl_xor(v, 4, 64));
        v = fminf(v, __shfl_xor(v, 8, 64));
        v = fminf(v, __shfl_xor(v, 16, 64));
        rm[a] = v;
    }
    if (tc == 0) {                               // lanes 0 & 32 of each wave
#pragma unroll
        for (int a = 0; a < 8; ++a) smin[a * 8 + tr] = rm[a];
    }
    __syncthreads();
    if (tid < 64) {
        int row = rowbase + tid;                 // matches smin[tid] mapping
        float v  = smin[tid];
        float ps = A[row].w;                     // |p|^2 (L1-hot reload)
        float contrib = (row < na) ? fmaxf(v + ps, 0.0f) : 0.0f;
#pragma unroll
        for (int off = 32; off > 0; off >>= 1)
            contrib += __shfl_down(contrib, off, 64);
        if (tid == 0) atomicAdd(out, contrib * (1.0f / B_ITEMS));
    }
}

extern "C" void kernel_launch(void* const* d_in, const int* in_sizes, int n_in,
                              void* d_out, int out_size, void* d_ws, size_t ws_size,
                              hipStream_t stream) {
    const float* pred = (const float*)d_in[0];
    const float* gt   = (const float*)d_in[1];
    const int*   mask = (const int*)  d_in[2];
    const float* fx   = (const float*)d_in[3];
    const float* fy   = (const float*)d_in[4];
    const float* cx   = (const float*)d_in[5];
    const float* cy   = (const float*)d_in[6];
    float* out = (float*)d_out;

    // ws: [0,256) cnt | pR 512K | gR 512K | pT 512K | gT 512K  (~2.1 MB)
    char* ws = (char*)d_ws;
    size_t SEG = (size_t)B_ITEMS * N_PTS * 16;
    int*    cnt = (int*)ws;
    float4* pR  = (float4*)(ws + 256);
    float4* gR  = (float4*)(ws + 256 + SEG);
    float4* pT  = (float4*)(ws + 256 + 2 * SEG);
    float4* gT  = (float4*)(ws + 256 + 3 * SEG);

    hipMemsetAsync(cnt, 0, 16, stream);

    prep_kernel<<<dim3(256), 256, 0, stream>>>(
        pred, gt, mask, fx, fy, cx, cy, cnt, pR, gR, pT, gT, out);

    chamfer_kernel<<<dim3(CH_GRID), 256, 0, stream>>>(
        cnt, pR, gR, pT, gT, out);
}